// Round 10
// baseline (71.736 us; speedup 1.0000x reference)
//
#include <hip/hip_runtime.h>
#include <stdint.h>
#include <math.h>

#define NCLS 81
#define NFG  80
#define NPI  1024
#define NIMG 8
#define DETS 100
#define SCORE_T 0.05f
#define NMS_T   0.5f
#define NCAND   (NFG * DETS)   // 8000
#define CAND_CAP 1024
#define ROWS 64                // rows per softmax block

static constexpr float BBOX_CLIP = 4.1351665567423557f; // log(1000/16)

// readlane: uniform broadcast via VALU->SGPR (no LDS crossbar)
__device__ __forceinline__ float rlf(float v, int i) {
#if __has_builtin(__builtin_amdgcn_readlane)
    return __uint_as_float((unsigned)__builtin_amdgcn_readlane((int)__float_as_uint(v), i));
#else
    return __shfl(v, i, 64);
#endif
}

// ---------------- Kernel 1: softmax -> transposed prob matrix (proven) --------
__global__ __launch_bounds__(256) void softmax_probT(
    const float* __restrict__ logits, float* __restrict__ probT, int M)
{
    __shared__ float tile[ROWS * NCLS];
    __shared__ float mx[ROWS], dn[ROWS];
    int t = threadIdx.x;
    int rbase = blockIdx.x * ROWS;
    for (int idx = t; idx < ROWS * NCLS; idx += 256)
        tile[idx] = logits[(size_t)rbase * NCLS + idx];
    __syncthreads();
    if (t < ROWS) {
        const float* r = tile + t * NCLS;
        float m = r[0];
        #pragma unroll
        for (int j = 1; j < NCLS; ++j) m = fmaxf(m, r[j]);
        float s = 0.f;
        #pragma unroll
        for (int j = 0; j < NCLS; ++j) s += expf(r[j] - m);
        mx[t] = m; dn[t] = s;
    }
    __syncthreads();
    for (int o = t; o < ROWS * NFG; o += 256) {
        int r = o & 63;
        int c = o >> 6;
        probT[(size_t)c * M + rbase + r] = expf(tile[r * NCLS + (c + 1)] - mx[r]) / dn[r];
    }
}

// ---------------- Kernel 2: single-wave per-(image,class) NMS -----------------
// key = score_bits<<32 | (1023-m)<<10 | append_pos
__global__ __launch_bounds__(64) void per_class_nms(
    const float* __restrict__ probT, const float* __restrict__ boxreg,
    const float* __restrict__ props, const int* __restrict__ hptr,
    const int* __restrict__ wptr, int* __restrict__ out_cnt,
    float* __restrict__ out_score, unsigned* __restrict__ out_key,
    float* __restrict__ out_box, int M)
{
    int pid = blockIdx.x;           // 0..639
    int img = pid / NFG;
    int c   = pid % NFG;
    int cls = c + 1;
    int lane = threadIdx.x;

    __shared__ unsigned long long pkey[NPI];   // 8KB, append order
    __shared__ unsigned long long skey[NPI];   // 8KB, sorted (n>64 path only)
    __shared__ float pbox[NPI][4];             // 16KB, by append pos
    __shared__ unsigned long long remv[16];

    float W1 = (float)(*wptr - 1);
    float H1 = (float)(*hptr - 1);

    int cnt = 0;  // wave-uniform
    const float* pT = probT + (size_t)c * M + img * NPI;

    // ---- append phase: ballot-compacted, no atomics ----
    #pragma unroll
    for (int it = 0; it < NPI / 256; ++it) {       // 4 iterations
        float4 pv = *(const float4*)(pT + it * 256 + lane * 4);
        float pr[4] = {pv.x, pv.y, pv.z, pv.w};
        #pragma unroll
        for (int j = 0; j < 4; ++j) {
            bool pass = pr[j] > SCORE_T;
            unsigned long long bal = __ballot(pass);
            if (pass) {
                int m = it * 256 + lane * 4 + j;
                int g = img * NPI + m;
                int mypos = cnt + __popcll(bal & ((1ULL << lane) - 1ULL));
                const float4 pb = *(const float4*)(props + (size_t)g * 4);
                float x1 = pb.x, y1 = pb.y, x2 = pb.z, y2 = pb.w;
                float w  = x2 - x1 + 1.0f, h = y2 - y1 + 1.0f;
                float cx = x1 + 0.5f * w,  cy = y1 + 0.5f * h;
                const float4 rc = *(const float4*)(boxreg + (size_t)g * (4 * NCLS) + 4 * cls);
                float dx = rc.x / 10.0f, dy = rc.y / 10.0f;
                float dw = fminf(rc.z / 5.0f, BBOX_CLIP);
                float dh = fminf(rc.w / 5.0f, BBOX_CLIP);
                float pcx = dx * w + cx, pcy = dy * h + cy;
                float pw = expf(dw) * w, ph = expf(dh) * h;
                float bx1 = fminf(fmaxf(pcx - 0.5f * pw, 0.f), W1);
                float by1 = fminf(fmaxf(pcy - 0.5f * ph, 0.f), H1);
                float bx2 = fminf(fmaxf(pcx + 0.5f * pw - 1.0f, 0.f), W1);
                float by2 = fminf(fmaxf(pcy + 0.5f * ph - 1.0f, 0.f), H1);
                pbox[mypos][0] = bx1; pbox[mypos][1] = by1;
                pbox[mypos][2] = bx2; pbox[mypos][3] = by2;
                pkey[mypos] = ((unsigned long long)__float_as_uint(pr[j]) << 32)
                            | ((unsigned)(NPI - 1 - m) << 10) | (unsigned)mypos;
            }
            cnt += __popcll(bal);
        }
    }
    int n = cnt;
    __syncthreads();   // 1 wave: compiles to a cheap waitcnt+barrier

    if (n <= 64) {
        // ================= hot path: zero further barriers =================
        unsigned long long k = (lane < n) ? pkey[lane] : 0ULL;
        #pragma unroll
        for (int kk = 2; kk <= 64; kk <<= 1) {
            #pragma unroll
            for (int j = kk >> 1; j > 0; j >>= 1) {
                unsigned long long o = __shfl_xor(k, j, 64);
                bool take_max = (((lane & kk) == 0) == ((lane & j) == 0));
                k = take_max ? (k > o ? k : o) : (k < o ? k : o);
            }
        }
        bool valid = (lane < n);
        float bx1 = 0.f, by1 = 0.f, bx2 = 0.f, by2 = 0.f, area = 0.f;
        if (valid) {
            int pos = (int)(k & 0x3FFu);
            bx1 = pbox[pos][0]; by1 = pbox[pos][1];
            bx2 = pbox[pos][2]; by2 = pbox[pos][3];
            area = (bx2 - bx1 + 1.f) * (by2 - by1 + 1.f);
        }
        unsigned long long sup = 0ULL;
        for (int i = 0; i < n; ++i) {
            if ((sup >> i) & 1ULL) continue;       // wave-uniform skip
            float ax1 = rlf(bx1, i), ay1 = rlf(by1, i);
            float ax2 = rlf(bx2, i), ay2 = rlf(by2, i);
            float aarea = rlf(area, i);
            bool s = false;
            if (valid && lane > i) {
                float xx1 = fmaxf(ax1, bx1), yy1 = fmaxf(ay1, by1);
                float xx2 = fminf(ax2, bx2), yy2 = fminf(ay2, by2);
                float iw = fmaxf(xx2 - xx1 + 1.f, 0.f);
                float ih = fmaxf(yy2 - yy1 + 1.f, 0.f);
                float inter = iw * ih;
                s = inter / (aarea + area - inter) > NMS_T;
            }
            sup |= __ballot(s);
        }
        bool kept = valid && !((sup >> lane) & 1ULL);
        unsigned long long keptm = __ballot(kept);
        int rank = __popcll(keptm & ((1ULL << lane) - 1ULL));
        if (kept && rank < DETS) {
            int slot = pid * DETS + rank;
            out_score[slot] = __uint_as_float((unsigned)(k >> 32));
            out_key[slot] = (unsigned)(c * NPI + lane);   // lane = sorted rank
            out_box[slot * 4 + 0] = bx1; out_box[slot * 4 + 1] = by1;
            out_box[slot * 4 + 2] = bx2; out_box[slot * 4 + 3] = by2;
        }
        if (lane == 0) {
            int tot = __popcll(keptm);
            out_cnt[pid] = tot < DETS ? tot : DETS;
        }
        return;
    }

    // ================= rare path: 64 < n <= 1024, single wave =================
    // rank-order sort into skey (keys unique)
    for (int i = lane; i < n; i += 64) {
        unsigned long long ki = pkey[i];
        int r = 0;
        for (int j = 0; j < n; ++j) r += (pkey[j] > ki) ? 1 : 0;
        skey[r] = ki;
    }
    if (lane < 16) remv[lane] = 0ULL;
    __syncthreads();

    int nch = (n + 63) >> 6;
    for (int a = 0; a < nch; ++a) {
        int ea = a * 64 + lane;
        bool va = ea < n;
        float bx1 = 0.f, by1 = 0.f, bx2 = 0.f, by2 = 0.f, area = 0.f;
        if (va) {
            int pos = (int)(skey[ea] & 0x3FFu);
            bx1 = pbox[pos][0]; by1 = pbox[pos][1];
            bx2 = pbox[pos][2]; by2 = pbox[pos][3];
            area = (bx2 - bx1 + 1.f) * (by2 - by1 + 1.f);
        }
        unsigned long long sup = remv[a];
        int lim = (n - a * 64 < 64) ? (n - a * 64) : 64;
        // in-chunk serial
        for (int i = 0; i < lim; ++i) {
            if ((sup >> i) & 1ULL) continue;
            float ax1 = rlf(bx1, i), ay1 = rlf(by1, i);
            float ax2 = rlf(bx2, i), ay2 = rlf(by2, i);
            float aarea = rlf(area, i);
            bool s = false;
            if (va && lane > i) {
                float xx1 = fmaxf(ax1, bx1), yy1 = fmaxf(ay1, by1);
                float xx2 = fminf(ax2, bx2), yy2 = fminf(ay2, by2);
                float iw = fmaxf(xx2 - xx1 + 1.f, 0.f);
                float ih = fmaxf(yy2 - yy1 + 1.f, 0.f);
                float inter = iw * ih;
                s = inter / (aarea + area - inter) > NMS_T;
            }
            sup |= __ballot(s);
        }
        if (lane == 0) remv[a] = sup;
        // cross-chunk suppression of later chunks
        for (int b = a + 1; b < nch; ++b) {
            int eb = b * 64 + lane;
            bool vb = eb < n;
            float cx1 = 0.f, cy1 = 0.f, cx2 = 0.f, cy2 = 0.f, carea = 0.f;
            if (vb) {
                int pos = (int)(skey[eb] & 0x3FFu);
                cx1 = pbox[pos][0]; cy1 = pbox[pos][1];
                cx2 = pbox[pos][2]; cy2 = pbox[pos][3];
                carea = (cx2 - cx1 + 1.f) * (cy2 - cy1 + 1.f);
            }
            unsigned long long supb = 0ULL;
            for (int i = 0; i < lim; ++i) {
                if ((sup >> i) & 1ULL) continue;   // only alive pivots suppress
                float ax1 = rlf(bx1, i), ay1 = rlf(by1, i);
                float ax2 = rlf(bx2, i), ay2 = rlf(by2, i);
                float aarea = rlf(area, i);
                bool s = false;
                if (vb) {
                    float xx1 = fmaxf(ax1, cx1), yy1 = fmaxf(ay1, cy1);
                    float xx2 = fminf(ax2, cx2), yy2 = fminf(ay2, cy2);
                    float iw = fmaxf(xx2 - xx1 + 1.f, 0.f);
                    float ih = fmaxf(yy2 - yy1 + 1.f, 0.f);
                    float inter = iw * ih;
                    s = inter / (aarea + carea - inter) > NMS_T;
                }
                supb |= __ballot(s);
            }
            if (lane == 0) remv[b] |= supb;
            __syncthreads();
        }
        __syncthreads();
    }

    // output: ranks among kept, sorted order
    unsigned long long vmasks[16];
    int base[17];
    base[0] = 0;
    for (int ch = 0; ch < nch; ++ch) {
        int rem = n - ch * 64;
        unsigned long long vm = (rem >= 64) ? ~0ULL : ((1ULL << rem) - 1ULL);
        vmasks[ch] = vm;
        base[ch + 1] = base[ch] + __popcll(~remv[ch] & vm);
    }
    for (int e = lane; e < n; e += 64) {
        int ch = e >> 6;
        unsigned long long rm = remv[ch];
        bool kept = !((rm >> (e & 63)) & 1ULL);
        if (kept) {
            int r = base[ch] + __popcll(~rm & vmasks[ch] & ((1ULL << (e & 63)) - 1ULL));
            if (r < DETS) {
                unsigned long long ki = skey[e];
                int pos = (int)(ki & 0x3FFu);
                int slot = pid * DETS + r;
                out_score[slot] = __uint_as_float((unsigned)(ki >> 32));
                out_key[slot] = (unsigned)(c * NPI + e);
                out_box[slot * 4 + 0] = pbox[pos][0];
                out_box[slot * 4 + 1] = pbox[pos][1];
                out_box[slot * 4 + 2] = pbox[pos][2];
                out_box[slot * 4 + 3] = pbox[pos][3];
            }
        }
    }
    if (lane == 0) {
        int tot = base[nch];
        out_cnt[pid] = tot < DETS ? tot : DETS;
    }
}

// ---------------- Kernel 3: per-image top-100, radix-select + rank write (proven) ----
__device__ __forceinline__ void suffix_select256(
    unsigned* hist, unsigned* wtot, int K, int* outB, unsigned* outAbove)
{
    int t = threadIdx.x, lane = t & 63, w = t >> 6;
    unsigned loc[16]; unsigned ps = 0;
    #pragma unroll
    for (int j = 0; j < 16; ++j) { loc[j] = hist[t * 16 + j]; ps += loc[j]; }
    unsigned v = ps;
    #pragma unroll
    for (int off = 1; off < 64; off <<= 1) {
        unsigned u = __shfl_down(v, off, 64);
        v += (lane + off < 64) ? u : 0u;
    }
    if (lane == 0) wtot[w] = v;
    __syncthreads();
    unsigned woff = 0;
    for (int w2 = w + 1; w2 < 4; ++w2) woff += wtot[w2];
    unsigned base = v + woff - ps;
    unsigned suf = 0;
    #pragma unroll
    for (int j = 15; j >= 0; --j) {
        unsigned A = base + suf;
        if ((int)A < K && (int)(A + loc[j]) >= K) { *outB = t * 16 + j; *outAbove = A; }
        suf += loc[j];
    }
    __syncthreads();
}

__global__ __launch_bounds__(256) void topk_merge(
    const int* __restrict__ cnts, const float* __restrict__ escore,
    const unsigned* __restrict__ ekey, const float* __restrict__ ebox,
    float* __restrict__ out)
{
    int img = blockIdx.x;
    __shared__ unsigned sc[NCAND];
    __shared__ unsigned hist[4096];
    __shared__ unsigned long long cand[CAND_CAP];
    __shared__ int scnts[NFG];
    __shared__ unsigned wtot[4];
    __shared__ int sB1, sB2, sNc;
    __shared__ unsigned sAb1, sAb2;

    int t = threadIdx.x;
    if (t < NFG) scnts[t] = cnts[img * NFG + t];
    if (t == 0) { sB1 = 0; sB2 = 0; sNc = 0; sAb1 = 0; sAb2 = 0; }
    for (int i = t; i < 4096; i += 256) hist[i] = 0;
    __syncthreads();

    for (int p = t; p < NCAND; p += 256) {
        unsigned fb = 0;
        if ((p % DETS) < scnts[p / DETS]) fb = __float_as_uint(escore[img * NCAND + p]);
        sc[p] = fb;
        if (fb) atomicAdd(&hist[fb >> 19], 1u);
    }
    __syncthreads();
    suffix_select256(hist, wtot, DETS, &sB1, &sAb1);
    int B1 = sB1; unsigned ab1 = sAb1;

    for (int i = t; i < 4096; i += 256) hist[i] = 0;
    __syncthreads();
    for (int p = t; p < NCAND; p += 256) {
        unsigned fb = sc[p];
        if (fb && (int)(fb >> 19) == B1) atomicAdd(&hist[(fb >> 7) & 0xFFFu], 1u);
    }
    __syncthreads();
    suffix_select256(hist, wtot, DETS - (int)ab1, &sB2, &sAb2);
    int B2 = sB2;

    for (int p = t; p < NCAND; p += 256) {
        unsigned fb = sc[p];
        if (fb) {
            int d1 = (int)(fb >> 19);
            bool ok = d1 > B1 || (d1 == B1 && (int)((fb >> 7) & 0xFFFu) >= B2);
            if (ok) {
                int pos = atomicAdd(&sNc, 1);
                if (pos < CAND_CAP) {
                    unsigned fk = ekey[img * NCAND + p];
                    cand[pos] = ((unsigned long long)fb << 32)
                              | (((0x1FFFFu - fk) << 13) | (unsigned)p);
                }
            }
        }
    }
    __syncthreads();
    int nc = sNc < CAND_CAP ? sNc : CAND_CAP;

    float* oScore = out;
    float* oBox   = out + NIMG * DETS;
    float* oLab   = out + NIMG * DETS * 5;

    for (int k = t; k < DETS; k += 256) {
        if (k >= nc) {
            int o = img * DETS + k;
            oScore[o] = 0.f;
            oBox[o * 4 + 0] = 0.f; oBox[o * 4 + 1] = 0.f;
            oBox[o * 4 + 2] = 0.f; oBox[o * 4 + 3] = 0.f;
            oLab[o] = 0.f;
        }
    }

    for (int i = t; i < nc; i += 256) {
        unsigned long long ki = cand[i];
        int r = 0;
        for (int j = 0; j < nc; ++j) r += (cand[j] > ki) ? 1 : 0;
        if (r < DETS) {
            float scv = __uint_as_float((unsigned)(ki >> 32));
            unsigned low = (unsigned)(ki & 0xFFFFFFFFu);
            unsigned flatkey = 0x1FFFFu - ((low >> 13) & 0x1FFFFu);
            int p = (int)(low & 0x1FFFu);
            int gp = img * NCAND + p;
            int o = img * DETS + r;
            oScore[o] = scv;
            oBox[o * 4 + 0] = ebox[gp * 4 + 0];
            oBox[o * 4 + 1] = ebox[gp * 4 + 1];
            oBox[o * 4 + 2] = ebox[gp * 4 + 2];
            oBox[o * 4 + 3] = ebox[gp * 4 + 3];
            oLab[o] = (float)((flatkey >> 10) + 1);
        }
    }
}

extern "C" void kernel_launch(void* const* d_in, const int* in_sizes, int n_in,
                              void* d_out, int out_size, void* d_ws, size_t ws_size,
                              hipStream_t stream) {
    const float* logits = (const float*)d_in[0];
    const float* boxreg = (const float*)d_in[1];
    const float* props  = (const float*)d_in[2];
    const int*   hptr   = (const int*)d_in[3];
    const int*   wptr   = (const int*)d_in[4];
    float* out = (float*)d_out;
    int M = in_sizes[0] / NCLS; // 8192

    char* ws = (char*)d_ws;
    float*    probT  = (float*)ws;    ws += (size_t)NFG * M * sizeof(float);
    int*      gcnt   = (int*)ws;      ws += (size_t)NIMG * NFG * sizeof(int);
    float*    escore = (float*)ws;    ws += (size_t)NIMG * NCAND * sizeof(float);
    unsigned* ekey   = (unsigned*)ws; ws += (size_t)NIMG * NCAND * sizeof(unsigned);
    float*    ebox   = (float*)ws;    ws += (size_t)NIMG * NCAND * 4 * sizeof(float);

    softmax_probT<<<M / ROWS, 256, 0, stream>>>(logits, probT, M);
    per_class_nms<<<NIMG * NFG, 64, 0, stream>>>(
        probT, boxreg, props, hptr, wptr, gcnt, escore, ekey, ebox, M);
    topk_merge<<<NIMG, 256, 0, stream>>>(gcnt, escore, ekey, ebox, out);
}